// Round 10
// baseline (331.563 us; speedup 1.0000x reference)
//
#include <hip/hip_runtime.h>

#define NN 4096
#define DD 64
#define KK 5
#define NBINS 1024
#define BINMUL 2.0f     // fallback hist bin width 0.5 over [0, 512)
#define RMED 8388607u   // (NN*NN - 1) / 2
#define MBUF_FLOATS 8192u  // per-block LDS gather capacity (reuses tiles)

typedef short short8 __attribute__((ext_vector_type(8)));
typedef float f32x4 __attribute__((ext_vector_type(4)));

struct Ctrl {
  unsigned wcount;   // window-gathered count (MODE 0)
  unsigned wover;    // LDS gather overflow / cap overflow flag
  unsigned below;    // exact count of d < loE (MODE 0)
  unsigned gcount;   // fallback-gathered count (MODE 1)
  unsigned sel_bin;  // fallback selected bin
  unsigned rank;     // fallback rank within sel_bin
  unsigned spref;    // radix prefix
  unsigned srank;    // remaining radix rank
  unsigned use_pow;  // kernel_scales == [0.5,1,2,4,8]
  float median;
  float c2;          // base*0.5*log2(e)
  float scales[KK];
};

__device__ inline bool window_ok(const Ctrl* c, unsigned cap) {
  return (c->wover == 0u) && (c->wcount <= cap) && (c->below <= RMED) &&
         ((RMED - c->below) < c->wcount);
}
__device__ inline float fast_exp2(float x) {
  float r;
  asm("v_exp_f32 %0, %1" : "=v"(r) : "v"(x));
  return r;
}
__device__ inline unsigned short bf16_rn(float f) {
  unsigned u = __float_as_uint(f);
  return (unsigned short)((u + 0x7FFFu + ((u >> 16) & 1u)) >> 16);
}
__device__ inline float bf16_val(unsigned short h) {
  return __uint_as_float(((unsigned)h) << 16);
}

// ---------------- fused split (f32 -> bf16 hi/lo) + row norms ----------------
__global__ void __launch_bounds__(256)
splitnorms_kernel(const float* __restrict__ x, const float* __restrict__ y,
                  short* __restrict__ xhi, short* __restrict__ xlo,
                  short* __restrict__ yhi, short* __restrict__ ylo,
                  float* __restrict__ xn, float* __restrict__ yn) {
  unsigned g = blockIdx.x * 256u + threadIdx.x;  // float4 id 0..131071
  const float* src; short *dhi, *dlo; float* nrm; unsigned local;
  if (g < 65536u) { src = x; dhi = xhi; dlo = xlo; nrm = xn; local = g; }
  else { src = y; dhi = yhi; dlo = ylo; nrm = yn; local = g - 65536u; }
  float4 v = *(const float4*)(src + (size_t)local * 4);
  unsigned short h0 = bf16_rn(v.x), h1 = bf16_rn(v.y), h2 = bf16_rn(v.z), h3 = bf16_rn(v.w);
  unsigned short l0 = bf16_rn(v.x - bf16_val(h0));
  unsigned short l1 = bf16_rn(v.y - bf16_val(h1));
  unsigned short l2 = bf16_rn(v.z - bf16_val(h2));
  unsigned short l3 = bf16_rn(v.w - bf16_val(h3));
  unsigned long long H = (unsigned long long)h0 | ((unsigned long long)h1 << 16) |
                         ((unsigned long long)h2 << 32) | ((unsigned long long)h3 << 48);
  unsigned long long L = (unsigned long long)l0 | ((unsigned long long)l1 << 16) |
                         ((unsigned long long)l2 << 32) | ((unsigned long long)l3 << 48);
  *(unsigned long long*)((char*)dhi + (size_t)local * 8) = H;
  *(unsigned long long*)((char*)dlo + (size_t)local * 8) = L;
  float part = v.x * v.x;
  part = fmaf(v.y, v.y, part);
  part = fmaf(v.z, v.z, part);
  part = fmaf(v.w, v.w, part);
#pragma unroll
  for (int off = 1; off < 16; off <<= 1) part += __shfl_xor(part, off);
  if ((threadIdx.x & 15) == 0) nrm[local >> 4] = part;
}

// ---------------- MFMA pair-tile kernel (round-8 staging, proven) ----------------
// 128x128 tile, 4 waves of 64x64, bf16x2 split (hihi + hilo + lohi).
// LDS: [row][hi/lo][k] bf16, row stride 256B, XOR-swizzled ((row&7)<<4).
// MODE 0: below-count + window gather          (common path)
// MODE 3: fallback full hist + fused bin select (early-exit if window ok)
// MODE 1: fallback gather of sel_bin            (early-exit if window ok)
// MODE 2: kernel sums (z: 0=xx 1=yy 2=zz)
template <int MODE>
__global__ void __launch_bounds__(256)
pair_kernel(const short* __restrict__ xhi, const short* __restrict__ xlo,
            const short* __restrict__ yhi, const short* __restrict__ ylo,
            const float* __restrict__ xn, const float* __restrict__ yn,
            unsigned* __restrict__ hist, Ctrl* __restrict__ ctrl,
            float* __restrict__ buf, double* __restrict__ S,
            unsigned* __restrict__ tick, float loE, float hiE, unsigned cap) {
  if (MODE == 1 || MODE == 3) {
    if (window_ok(ctrl, cap)) return;  // common path: nothing to do
  }
  __shared__ __align__(16) char smem[65536];
  __shared__ unsigned bcnt, gbase, lastflag;
  char* As = smem;
  char* Bs = smem + 32768;

  int t = threadIdx.x;
  int sel = (MODE == 2) ? blockIdx.z : 0;
  const short* Ah = (sel == 1) ? yhi : xhi;
  const short* Al = (sel == 1) ? ylo : xlo;
  const short* Bh = (sel == 0) ? xhi : yhi;
  const short* Bl = (sel == 0) ? xlo : ylo;
  const float* An = (sel == 1) ? yn : xn;
  const float* Bn = (sel == 0) ? xn : yn;

  int rowBase = blockIdx.y * 128;
  int colBase = blockIdx.x * 128;

  int lane = t & 63, wid = t >> 6;
  int wr = (wid >> 1) * 64, wc = (wid & 1) * 64;
  int lrow = lane & 15;
  int lk8 = (lane >> 4) * 8;
  int lswz = (lane & 7) << 4;

  // ---- stage 4x16KB tiles (coalesced 16B chunks, swizzled LDS writes) ----
  {
    const char* gAh = (const char*)Ah + (size_t)rowBase * 128;
    const char* gAl = (const char*)Al + (size_t)rowBase * 128;
    const char* gBh = (const char*)Bh + (size_t)colBase * 128;
    const char* gBl = (const char*)Bl + (size_t)colBase * 128;
    short8 rAh[4], rAl[4], rBh[4], rBl[4];
#pragma unroll
    for (int i = 0; i < 4; ++i) {
      int o = t * 16 + i * 4096;
      rAh[i] = *(const short8*)(gAh + o);
      rAl[i] = *(const short8*)(gAl + o);
      rBh[i] = *(const short8*)(gBh + o);
      rBl[i] = *(const short8*)(gBl + o);
    }
#pragma unroll
    for (int i = 0; i < 4; ++i) {
      int o = t * 16 + i * 4096;
      int rr = o >> 7;
      int cc = (o >> 4) & 7;
      int db = (rr * 256 + cc * 16) ^ ((rr & 7) << 4);
      *(short8*)(As + db) = rAh[i];
      *(short8*)(As + db + 128) = rAl[i];
      *(short8*)(Bs + db) = rBh[i];
      *(short8*)(Bs + db + 128) = rBl[i];
    }
  }
  __syncthreads();

  // ---- MFMA compute: acc += Ahi*Bhi + Ahi*Blo + Alo*Bhi ----
  f32x4 acc[4][4] = {};
#pragma unroll
  for (int kc = 0; kc < 2; ++kc) {
    short8 ah[4], al[4], bh[4], bl[4];
#pragma unroll
    for (int m = 0; m < 4; ++m) {
      int by = ((wr + m * 16 + lrow) * 256 + (lk8 + kc * 32) * 2) ^ lswz;
      ah[m] = *(const short8*)(As + by);
      al[m] = *(const short8*)(As + by + 128);
    }
#pragma unroll
    for (int n = 0; n < 4; ++n) {
      int by = ((wc + n * 16 + lrow) * 256 + (lk8 + kc * 32) * 2) ^ lswz;
      bh[n] = *(const short8*)(Bs + by);
      bl[n] = *(const short8*)(Bs + by + 128);
    }
#pragma unroll
    for (int m = 0; m < 4; ++m)
#pragma unroll
      for (int n = 0; n < 4; ++n) {
        acc[m][n] = __builtin_amdgcn_mfma_f32_16x16x32_bf16(ah[m], bh[n], acc[m][n], 0, 0, 0);
        acc[m][n] = __builtin_amdgcn_mfma_f32_16x16x32_bf16(ah[m], bl[n], acc[m][n], 0, 0, 0);
        acc[m][n] = __builtin_amdgcn_mfma_f32_16x16x32_bf16(al[m], bh[n], acc[m][n], 0, 0, 0);
      }
  }

  // C/D map (HW-verified m89): col = lane&15, row = (lane>>4)*4 + reg
  float anv[16], bnv[4];
#pragma unroll
  for (int m = 0; m < 4; ++m)
#pragma unroll
    for (int r = 0; r < 4; ++r)
      anv[m * 4 + r] = An[rowBase + wr + m * 16 + (lane >> 4) * 4 + r];
#pragma unroll
  for (int n = 0; n < 4; ++n) bnv[n] = Bn[colBase + wc + n * 16 + lrow];

  __syncthreads();  // all LDS fragment reads complete; smem reusable

  if (MODE == 0) {
    float* mbuf = (float*)As;  // 8192-float gather buffer
    if (t == 0) bcnt = 0;
    __syncthreads();
    int below = 0;
#pragma unroll
    for (int m = 0; m < 4; ++m)
#pragma unroll
      for (int n = 0; n < 4; ++n)
#pragma unroll
        for (int r = 0; r < 4; ++r) {
          float d = (anv[m * 4 + r] + bnv[n]) - 2.0f * acc[m][n][r];
          below += (d < loE) ? 1 : 0;
          if (d >= loE && d < hiE) {
            unsigned idx = atomicAdd(&bcnt, 1u);
            if (idx < MBUF_FLOATS) mbuf[idx] = d - 100.0f;  // exact for d in [50,200]
            else ctrl->wover = 1u;
          }
        }
#pragma unroll
    for (int off = 32; off > 0; off >>= 1) below += __shfl_down(below, off);
    if (lane == 0) atomicAdd(&ctrl->below, (unsigned)below);
    __syncthreads();
    unsigned cnt = min(bcnt, MBUF_FLOATS);
    if (t == 0) gbase = atomicAdd(&ctrl->wcount, cnt);
    __syncthreads();
    for (unsigned i = t; i < cnt; i += 256) {
      unsigned gi = gbase + i;
      if (gi < cap) buf[gi] = mbuf[i];
    }
  }

  if (MODE == 3) {  // fallback: full histogram + fused bin select
    unsigned* h = (unsigned*)Bs;  // 4KB
    for (int i = t; i < NBINS; i += 256) h[i] = 0;
    if (t == 0) lastflag = 0;
    __syncthreads();
#pragma unroll
    for (int m = 0; m < 4; ++m)
#pragma unroll
      for (int n = 0; n < 4; ++n)
#pragma unroll
        for (int r = 0; r < 4; ++r) {
          float d = (anv[m * 4 + r] + bnv[n]) - 2.0f * acc[m][n][r];
          int b = (int)(d * BINMUL);
          b = min(max(b, 0), NBINS - 1);
          atomicAdd(&h[b], 1u);
        }
    __syncthreads();
    for (int i = t; i < NBINS; i += 256)
      if (h[i]) atomicAdd(&hist[i], h[i]);
    __threadfence();
    if (t == 0)
      lastflag = (atomicAdd(&tick[4], 1u) == gridDim.x * gridDim.y - 1u) ? 1u : 0u;
    __syncthreads();
    if (!lastflag) return;
    // last block: select bin of rank RMED (device-scope reads)
    unsigned* ps = h + NBINS;  // scratch
    unsigned loc[4]; unsigned s = 0;
#pragma unroll
    for (int i = 0; i < 4; ++i) { loc[i] = atomicAdd(&hist[t * 4 + i], 0u); s += loc[i]; }
    ps[t] = s;
    __syncthreads();
    for (int off = 1; off < 256; off <<= 1) {
      unsigned v = ps[t];
      unsigned add = (t >= off) ? ps[t - off] : 0u;
      __syncthreads();
      ps[t] = v + add;
      __syncthreads();
    }
    unsigned incl = ps[t], excl = incl - s;
    if (RMED >= excl && RMED < incl) {
      unsigned rank = RMED - excl;
      int bsel = -1;
#pragma unroll
      for (int i = 0; i < 4; ++i) {
        if (bsel < 0) {
          if (rank < loc[i]) bsel = t * 4 + i;
          else rank -= loc[i];
        }
      }
      ctrl->sel_bin = (unsigned)bsel;
      ctrl->rank = rank;
    }
  }

  if (MODE == 1) {  // fallback gather of sel_bin
    unsigned sb = ctrl->sel_bin;
    float* mbuf = (float*)As;
    if (t == 0) bcnt = 0;
    __syncthreads();
#pragma unroll
    for (int m = 0; m < 4; ++m)
#pragma unroll
      for (int n = 0; n < 4; ++n)
#pragma unroll
        for (int r = 0; r < 4; ++r) {
          float d = (anv[m * 4 + r] + bnv[n]) - 2.0f * acc[m][n][r];
          int b = (int)(d * BINMUL);
          b = min(max(b, 0), NBINS - 1);
          if ((unsigned)b == sb) {
            unsigned idx = atomicAdd(&bcnt, 1u);
            if (idx < MBUF_FLOATS) mbuf[idx] = d - 100.0f;
          }
        }
    __syncthreads();
    unsigned cnt = min(bcnt, MBUF_FLOATS);
    if (t == 0) gbase = atomicAdd(&ctrl->gcount, cnt);
    __syncthreads();
    for (unsigned i = t; i < cnt; i += 256) {
      unsigned gi = gbase + i;
      if (gi < cap) buf[gi] = mbuf[i];
    }
  }

  if (MODE == 2) {
    float s = 0.f;
    if (ctrl->use_pow) {
      float c2 = ctrl->c2, m2c2 = -2.0f * c2;
      float bnvc[4];
#pragma unroll
      for (int n = 0; n < 4; ++n) bnvc[n] = bnv[n] * c2;
#pragma unroll
      for (int i = 0; i < 16; ++i) anv[i] *= c2;
#pragma unroll
      for (int m = 0; m < 4; ++m)
#pragma unroll
        for (int n = 0; n < 4; ++n)
#pragma unroll
          for (int r = 0; r < 4; ++r) {
            float arg = fmaf(acc[m][n][r], m2c2, anv[m * 4 + r] + bnvc[n]);
            float u = fast_exp2(arg);               // exp(d*base*0.5)
            float u2 = u * u;
            float a = fmaf(u, u, u);                // u + u^2
            float u4 = u2 * u2, u8 = u4 * u4;
            float b = fmaf(u8, u8, u8);             // u^8 + u^16
            s += a; s += u4; s += b;
          }
    } else {
      float sc[KK];
#pragma unroll
      for (int k = 0; k < KK; ++k) sc[k] = ctrl->scales[k];
#pragma unroll
      for (int m = 0; m < 4; ++m)
#pragma unroll
        for (int n = 0; n < 4; ++n)
#pragma unroll
          for (int r = 0; r < 4; ++r) {
            float d = (anv[m * 4 + r] + bnv[n]) - 2.0f * acc[m][n][r];
            float e = 0.f;
#pragma unroll
            for (int k = 0; k < KK; ++k) e += expf(d * sc[k]);
            s += e;
          }
    }
    // diagonal handled analytically in finalize
    double sd = (double)s;
#pragma unroll
    for (int off = 32; off > 0; off >>= 1) sd += __shfl_down(sd, off);
    double* wsum = (double*)As;
    if ((t & 63) == 0) wsum[wid] = sd;
    __syncthreads();
    if (t == 0) atomicAdd(&S[sel], (wsum[0] + wsum[1]) + (wsum[2] + wsum[3]));
  }
}

// ---------------- fused radix round: grid hist + last-block scan ----------------
__global__ void __launch_bounds__(256)
radix_fused(Ctrl* __restrict__ ctrl, const float* __restrict__ buf,
            unsigned* __restrict__ gh, unsigned* __restrict__ tick,
            const float* __restrict__ ksc, int round, unsigned cap) {
  __shared__ unsigned h[256];
  __shared__ unsigned lastflag;
  int t = threadIdx.x;
  h[t] = 0;
  if (t == 0) lastflag = 0;
  __syncthreads();
  bool okw = window_ok(ctrl, cap);
  unsigned m = min(okw ? ctrl->wcount : ctrl->gcount, cap);
  unsigned pref = ctrl->spref;
  int shift = 24 - 8 * round;
  for (unsigned i = blockIdx.x * 256u + t; i < m; i += gridDim.x * 256u) {
    unsigned u = __float_as_uint(buf[i]);
    u ^= (u >> 31) ? 0xFFFFFFFFu : 0x80000000u;
    if (round == 0 || ((u ^ pref) >> (shift + 8)) == 0u)
      atomicAdd(&h[(u >> shift) & 255u], 1u);
  }
  __syncthreads();
  if (h[t]) atomicAdd(&gh[round * 256 + t], h[t]);
  __threadfence();
  if (t == 0)
    lastflag = (atomicAdd(&tick[round], 1u) == gridDim.x - 1u) ? 1u : 0u;
  __syncthreads();
  if (!lastflag) return;
  // last block scans this round's 256 bins
  unsigned rank = (round == 0) ? (okw ? RMED - ctrl->below : ctrl->rank) : ctrl->srank;
  unsigned c = atomicAdd(&gh[round * 256 + t], 0u);  // device-scope read
  h[t] = c;
  __syncthreads();
  for (int off = 1; off < 256; off <<= 1) {
    unsigned v = h[t];
    unsigned add = (t >= off) ? h[t - off] : 0u;
    __syncthreads();
    h[t] = v + add;
    __syncthreads();
  }
  unsigned incl = h[t], excl = incl - c;
  if (rank >= excl && rank < incl) {
    unsigned np = pref | ((unsigned)t << shift);
    ctrl->spref = np;
    ctrl->srank = rank - excl;
    if (round == 3) {
      unsigned u = (np & 0x80000000u) ? (np ^ 0x80000000u) : ~np;
      float med = __uint_as_float(u) + 100.0f;  // undo d-100 store
      ctrl->median = med;
      float base = -1.0f / med;
#pragma unroll
      for (int k = 0; k < KK; ++k) ctrl->scales[k] = base * ksc[k];
      ctrl->c2 = base * 0.5f * 1.44269504088896f;
      ctrl->use_pow = (ksc[0] == 0.5f && ksc[1] == 1.0f && ksc[2] == 2.0f &&
                       ksc[3] == 4.0f && ksc[4] == 8.0f) ? 1u : 0u;
    }
  }
}

// ---------------- finalize ----------------
__global__ void finalize_kernel(const double* __restrict__ S, float* __restrict__ out) {
  if (threadIdx.x == 0 && blockIdx.x == 0) {
    double offd = 1.0 / ((double)NN * (double)(NN - 1));
    double invK = 1.0 / (double)KK;
    double kxx = (S[0] * invK) - (double)NN;  // subtract diagonal (exp(0)=1, KK terms)
    double kyy = (S[1] * invK) - (double)NN;
    double kzz = S[2] * invK;
    double val = offd * (kxx + kyy) - 2.0 * kzz / ((double)NN * (double)NN);
    out[0] = (float)val;
  }
}

extern "C" void kernel_launch(void* const* d_in, const int* in_sizes, int n_in,
                              void* d_out, int out_size, void* d_ws, size_t ws_size,
                              hipStream_t stream) {
  const float* x = (const float*)d_in[0];
  const float* y = (const float*)d_in[1];
  const float* ksc = (const float*)d_in[2];

  char* ws = (char*)d_ws;
  double* S = (double*)ws;                 // 3 doubles @ 0
  unsigned* hist = (unsigned*)(ws + 64);   // 1024 u32  @ 64
  unsigned* gh = (unsigned*)(ws + 4160);   // 4*256 u32 @ 4160
  unsigned* tick = (unsigned*)(ws + 8256); // 8 u32     @ 8256
  Ctrl* ctrl = (Ctrl*)(ws + 8288);         // ~64B      @ 8288
  float* xn = (float*)(ws + 8448);
  float* yn = xn + NN;                     // ends @ 41216
  const size_t SPL = (size_t)NN * DD * 2;  // 512KB per split array
  short* xhi = (short*)(ws + 65536);
  short* xlo = (short*)(ws + 65536 + SPL);
  short* yhi = (short*)(ws + 65536 + 2 * SPL);
  short* ylo = (short*)(ws + 65536 + 3 * SPL);
  size_t bufoff = 65536 + 4 * SPL;         // @ 2162688
  float* buf = (float*)(ws + bufoff);

  size_t avail = (ws_size > bufoff) ? (ws_size - bufoff) / 4 : 0;
  unsigned cap = (unsigned)((avail < (size_t)(8u << 20)) ? avail : (size_t)(8u << 20));
  // narrow window around estimated median d~127.7 (sample-median sd ~0.007);
  // exact MODE3/MODE1 fallback covers a miss
  float loE, hiE;
  if (cap >= 600000u) { loE = 127.0f; hiE = 128.5f; }
  else                { loE = 127.0f; hiE = 128.0f; }

  hipMemsetAsync(ws, 0, 8448, stream);  // S, hist, gh, tick, ctrl

  splitnorms_kernel<<<512, 256, 0, stream>>>(x, y, xhi, xlo, yhi, ylo, xn, yn);
  pair_kernel<0><<<dim3(32, 32), 256, 0, stream>>>(xhi, xlo, yhi, ylo, xn, yn, hist, ctrl,
                                                   buf, S, tick, loE, hiE, cap);
  pair_kernel<3><<<dim3(32, 32), 256, 0, stream>>>(xhi, xlo, yhi, ylo, xn, yn, hist, ctrl,
                                                   buf, S, tick, loE, hiE, cap);
  pair_kernel<1><<<dim3(32, 32), 256, 0, stream>>>(xhi, xlo, yhi, ylo, xn, yn, hist, ctrl,
                                                   buf, S, tick, loE, hiE, cap);
  for (int r = 0; r < 4; ++r)
    radix_fused<<<192, 256, 0, stream>>>(ctrl, buf, gh, tick, ksc, r, cap);
  pair_kernel<2><<<dim3(32, 32, 3), 256, 0, stream>>>(xhi, xlo, yhi, ylo, xn, yn, hist, ctrl,
                                                      buf, S, tick, loE, hiE, cap);
  finalize_kernel<<<1, 64, 0, stream>>>(S, (float*)d_out);
}

// Round 11
// 230.072 us; speedup vs baseline: 1.4411x; 1.4411x over previous
//
#include <hip/hip_runtime.h>

#define NN 4096
#define DD 64
#define KK 5
#define NBINS 1024
#define BINMUL 2.0f    // coarse bin width 0.5 over [0, 512)
#define RMED 8388607u  // (NN*NN - 1) / 2
#define MBUF_CAP 8192u // per-block LDS gather capacity (reuses tiles)

typedef short short8 __attribute__((ext_vector_type(8)));
typedef float f32x4 __attribute__((ext_vector_type(4)));

struct Ctrl {
  unsigned wcount;   // window-gathered candidate count (MODE 0)
  unsigned wover;    // 1 if any block overflowed its LDS gather buffer
  unsigned gcount;   // fallback-gathered candidate count (MODE 1)
  unsigned sel_bin;  // selected coarse bin
  unsigned rank;     // rank (0-based) within selected bin (fallback path)
  unsigned ok;       // 1 = window path valid (skip MODE 1)
  unsigned wrank;    // rank within window candidates (window path)
  unsigned spref;    // radix-select prefix (built over 4 rounds)
  unsigned srank;    // remaining rank within prefix
  unsigned use_pow;  // 1 if kernel_scales == [0.5,1,2,4,8]
  float median;
  float c2;          // base*0.5*log2(e)
  float scales[KK];  // base*kernel_scales[k] (general fallback)
};

__device__ inline float fast_exp2(float x) {
  float r;
  asm("v_exp_f32 %0, %1" : "=v"(r) : "v"(x));
  return r;
}
__device__ inline unsigned short bf16_rn(float f) {
  unsigned u = __float_as_uint(f);
  return (unsigned short)((u + 0x7FFFu + ((u >> 16) & 1u)) >> 16);
}
__device__ inline float bf16_val(unsigned short h) {
  return __uint_as_float(((unsigned)h) << 16);
}

// ---------------- fused split (f32 -> bf16 hi/lo) + row norms ----------------
__global__ void __launch_bounds__(256)
splitnorms_kernel(const float* __restrict__ x, const float* __restrict__ y,
                  short* __restrict__ xhi, short* __restrict__ xlo,
                  short* __restrict__ yhi, short* __restrict__ ylo,
                  float* __restrict__ xn, float* __restrict__ yn) {
  unsigned g = blockIdx.x * 256u + threadIdx.x;  // float4 id 0..131071
  const float* src; short *dhi, *dlo; float* nrm; unsigned local;
  if (g < 65536u) { src = x; dhi = xhi; dlo = xlo; nrm = xn; local = g; }
  else { src = y; dhi = yhi; dlo = ylo; nrm = yn; local = g - 65536u; }
  float4 v = *(const float4*)(src + (size_t)local * 4);
  unsigned short h0 = bf16_rn(v.x), h1 = bf16_rn(v.y), h2 = bf16_rn(v.z), h3 = bf16_rn(v.w);
  unsigned short l0 = bf16_rn(v.x - bf16_val(h0));
  unsigned short l1 = bf16_rn(v.y - bf16_val(h1));
  unsigned short l2 = bf16_rn(v.z - bf16_val(h2));
  unsigned short l3 = bf16_rn(v.w - bf16_val(h3));
  unsigned long long H = (unsigned long long)h0 | ((unsigned long long)h1 << 16) |
                         ((unsigned long long)h2 << 32) | ((unsigned long long)h3 << 48);
  unsigned long long L = (unsigned long long)l0 | ((unsigned long long)l1 << 16) |
                         ((unsigned long long)l2 << 32) | ((unsigned long long)l3 << 48);
  *(unsigned long long*)((char*)dhi + (size_t)local * 8) = H;
  *(unsigned long long*)((char*)dlo + (size_t)local * 8) = L;
  float part = v.x * v.x;
  part = fmaf(v.y, v.y, part);
  part = fmaf(v.z, v.z, part);
  part = fmaf(v.w, v.w, part);
#pragma unroll
  for (int off = 1; off < 16; off <<= 1) part += __shfl_xor(part, off);
  if ((threadIdx.x & 15) == 0) nrm[local >> 4] = part;
}

// ---------------- MFMA pair-tile kernel (round-8 code, verbatim) ----------------
// 128x128 tile per block, 4 waves of 64x64, bf16x2 split (hihi+hilo+lohi).
// LDS per matrix: [row][kind hi/lo][k] bf16, row stride 256B, XOR-swizzle ((row&7)<<4).
// MODE 0: coarse hist + window gather (stores d-100)
// MODE 1: fallback gather of sel_bin (stores d-100); early-exit if ctrl->ok
// MODE 2: kernel sums (z=0: xx, z=1: yy, z=2: zz)
template <int MODE>
__global__ void __launch_bounds__(256)
pair_kernel(const short* __restrict__ xhi, const short* __restrict__ xlo,
            const short* __restrict__ yhi, const short* __restrict__ ylo,
            const float* __restrict__ xn, const float* __restrict__ yn,
            unsigned* __restrict__ hist, Ctrl* __restrict__ ctrl,
            float* __restrict__ buf, double* __restrict__ S,
            int lobin, int hibin, unsigned cap) {
  if (MODE == 1) {
    if (ctrl->ok) return;  // window path succeeded
  }
  __shared__ __align__(16) char smem[65536];
  char* As = smem;
  char* Bs = smem + 32768;

  int t = threadIdx.x;
  int sel = (MODE == 2) ? blockIdx.z : 0;
  const short* Ah = (sel == 1) ? yhi : xhi;
  const short* Al = (sel == 1) ? ylo : xlo;
  const short* Bh = (sel == 0) ? xhi : yhi;
  const short* Bl = (sel == 0) ? xlo : ylo;
  const float* An = (sel == 1) ? yn : xn;
  const float* Bn = (sel == 0) ? xn : yn;

  int rowBase = blockIdx.y * 128;
  int colBase = blockIdx.x * 128;

  int lane = t & 63, wid = t >> 6;
  int wr = (wid >> 1) * 64, wc = (wid & 1) * 64;
  int lrow = lane & 15;
  int lk8 = (lane >> 4) * 8;
  int lswz = (lane & 7) << 4;

  // ---- stage 4x16KB tiles (coalesced 16B chunks, swizzled LDS writes) ----
  {
    const char* gAh = (const char*)Ah + (size_t)rowBase * 128;
    const char* gAl = (const char*)Al + (size_t)rowBase * 128;
    const char* gBh = (const char*)Bh + (size_t)colBase * 128;
    const char* gBl = (const char*)Bl + (size_t)colBase * 128;
    short8 rAh[4], rAl[4], rBh[4], rBl[4];
#pragma unroll
    for (int i = 0; i < 4; ++i) {
      int o = t * 16 + i * 4096;
      rAh[i] = *(const short8*)(gAh + o);
      rAl[i] = *(const short8*)(gAl + o);
      rBh[i] = *(const short8*)(gBh + o);
      rBl[i] = *(const short8*)(gBl + o);
    }
#pragma unroll
    for (int i = 0; i < 4; ++i) {
      int o = t * 16 + i * 4096;
      int rr = o >> 7;
      int cc = (o >> 4) & 7;
      int db = (rr * 256 + cc * 16) ^ ((rr & 7) << 4);
      *(short8*)(As + db) = rAh[i];
      *(short8*)(As + db + 128) = rAl[i];
      *(short8*)(Bs + db) = rBh[i];
      *(short8*)(Bs + db + 128) = rBl[i];
    }
  }
  __syncthreads();

  // ---- MFMA compute: acc += Ahi*Bhi + Ahi*Blo + Alo*Bhi ----
  f32x4 acc[4][4] = {};
#pragma unroll
  for (int kc = 0; kc < 2; ++kc) {
    short8 ah[4], al[4], bh[4], bl[4];
#pragma unroll
    for (int m = 0; m < 4; ++m) {
      int by = ((wr + m * 16 + lrow) * 256 + (lk8 + kc * 32) * 2) ^ lswz;
      ah[m] = *(const short8*)(As + by);
      al[m] = *(const short8*)(As + by + 128);
    }
#pragma unroll
    for (int n = 0; n < 4; ++n) {
      int by = ((wc + n * 16 + lrow) * 256 + (lk8 + kc * 32) * 2) ^ lswz;
      bh[n] = *(const short8*)(Bs + by);
      bl[n] = *(const short8*)(Bs + by + 128);
    }
#pragma unroll
    for (int m = 0; m < 4; ++m)
#pragma unroll
      for (int n = 0; n < 4; ++n) {
        acc[m][n] = __builtin_amdgcn_mfma_f32_16x16x32_bf16(ah[m], bh[n], acc[m][n], 0, 0, 0);
        acc[m][n] = __builtin_amdgcn_mfma_f32_16x16x32_bf16(ah[m], bl[n], acc[m][n], 0, 0, 0);
        acc[m][n] = __builtin_amdgcn_mfma_f32_16x16x32_bf16(al[m], bh[n], acc[m][n], 0, 0, 0);
      }
  }

  // C/D map (HW-verified m89): col = lane&15, row = (lane>>4)*4 + reg
  float anv[16], bnv[4];
#pragma unroll
  for (int m = 0; m < 4; ++m)
#pragma unroll
    for (int r = 0; r < 4; ++r)
      anv[m * 4 + r] = An[rowBase + wr + m * 16 + (lane >> 4) * 4 + r];
#pragma unroll
  for (int n = 0; n < 4; ++n) bnv[n] = Bn[colBase + wc + n * 16 + lrow];

  __syncthreads();  // all LDS fragment reads complete; smem reusable

  if (MODE == 0 || MODE == 1) {
    unsigned* h = (unsigned*)Bs;   // 4KB hist (MODE 0)
    float* mbuf = (float*)As;      // 8192-float gather buffer
    __shared__ unsigned bcnt, gbase;
    if (MODE == 0)
      for (int i = t; i < NBINS; i += 256) h[i] = 0;
    if (t == 0) bcnt = 0;
    __syncthreads();
    unsigned sb = (MODE == 1) ? ctrl->sel_bin : 0u;
#pragma unroll
    for (int m = 0; m < 4; ++m)
#pragma unroll
      for (int n = 0; n < 4; ++n)
#pragma unroll
        for (int r = 0; r < 4; ++r) {
          float d = (anv[m * 4 + r] + bnv[n]) - 2.0f * acc[m][n][r];
          int b = (int)(d * BINMUL);
          b = min(max(b, 0), NBINS - 1);
          if (MODE == 0) {
            atomicAdd(&h[b], 1u);
            if (b >= lobin && b < hibin) {
              unsigned idx = atomicAdd(&bcnt, 1u);
              if (idx < MBUF_CAP) mbuf[idx] = d - 100.0f;  // exact (d in [100,200])
              else ctrl->wover = 1u;
            }
          } else {
            if ((unsigned)b == sb) {
              unsigned idx = atomicAdd(&bcnt, 1u);
              if (idx < MBUF_CAP) mbuf[idx] = d - 100.0f;
            }
          }
        }
    __syncthreads();
    if (MODE == 0)
      for (int i = t; i < NBINS; i += 256)
        if (h[i]) atomicAdd(&hist[i], h[i]);
    unsigned cnt = min(bcnt, MBUF_CAP);
    if (t == 0) gbase = atomicAdd(MODE == 0 ? &ctrl->wcount : &ctrl->gcount, cnt);
    __syncthreads();
    for (unsigned i = t; i < cnt; i += 256) {
      unsigned gi = gbase + i;
      if (gi < cap) buf[gi] = mbuf[i];
    }
  }

  if (MODE == 2) {
    float s = 0.f;
    if (ctrl->use_pow) {
      float c2 = ctrl->c2;
#pragma unroll
      for (int m = 0; m < 4; ++m)
#pragma unroll
        for (int n = 0; n < 4; ++n)
#pragma unroll
          for (int r = 0; r < 4; ++r) {
            float d = (anv[m * 4 + r] + bnv[n]) - 2.0f * acc[m][n][r];
            float u = fast_exp2(d * c2);  // exp(d*base*0.5)
            float u2 = u * u, u4 = u2 * u2, u8 = u4 * u4, u16 = u8 * u8;
            s += ((u + u2) + (u4 + u8)) + u16;
          }
    } else {
      float sc[KK];
#pragma unroll
      for (int k = 0; k < KK; ++k) sc[k] = ctrl->scales[k];
#pragma unroll
      for (int m = 0; m < 4; ++m)
#pragma unroll
        for (int n = 0; n < 4; ++n)
#pragma unroll
          for (int r = 0; r < 4; ++r) {
            float d = (anv[m * 4 + r] + bnv[n]) - 2.0f * acc[m][n][r];
            float e = 0.f;
#pragma unroll
            for (int k = 0; k < KK; ++k) e += expf(d * sc[k]);
            s += e;
          }
    }
    // diagonal handled analytically in finalize
    double sd = (double)s;
#pragma unroll
    for (int off = 32; off > 0; off >>= 1) sd += __shfl_down(sd, off);
    double* wsum = (double*)As;
    if ((t & 63) == 0) wsum[wid] = sd;
    __syncthreads();
    if (t == 0) atomicAdd(&S[sel], (wsum[0] + wsum[1]) + (wsum[2] + wsum[3]));
  }
}

// ---------------- find coarse bin of rank RMED (round-8 code, verbatim) ----------------
__global__ void __launch_bounds__(256)
select_bin_kernel(const unsigned* __restrict__ hist, Ctrl* __restrict__ ctrl,
                  int lobin, int hibin, unsigned cap) {
  __shared__ unsigned ps[256];
  __shared__ unsigned s_cumlo;
  int t = threadIdx.x;
  unsigned loc[NBINS / 256];
  unsigned s = 0;
#pragma unroll
  for (int i = 0; i < NBINS / 256; ++i) {
    loc[i] = hist[t * (NBINS / 256) + i];
    s += loc[i];
  }
  ps[t] = s;
  __syncthreads();
  for (int off = 1; off < 256; off <<= 1) {
    unsigned v = ps[t];
    unsigned add = (t >= off) ? ps[t - off] : 0u;
    __syncthreads();
    ps[t] = v + add;
    __syncthreads();
  }
  unsigned incl = ps[t], excl = incl - s;
  if (t == (lobin >> 2)) {  // exclusive cum below bin `lobin`
    unsigned c = excl;
    for (int i = 0; i < (lobin & 3); ++i) c += loc[i];
    s_cumlo = c;
  }
  __syncthreads();
  if (RMED >= excl && RMED < incl) {
    unsigned rank = RMED - excl;
    int bsel = -1;
#pragma unroll
    for (int i = 0; i < NBINS / 256; ++i) {
      if (bsel < 0) {
        if (rank < loc[i]) bsel = t * (NBINS / 256) + i;
        else rank -= loc[i];
      }
    }
    ctrl->sel_bin = (unsigned)bsel;
    ctrl->rank = rank;
    unsigned wrank = RMED - s_cumlo;
    unsigned ok = (bsel >= lobin && bsel < hibin && ctrl->wover == 0u &&
                   ctrl->wcount <= cap && wrank < ctrl->wcount) ? 1u : 0u;
    ctrl->wrank = wrank;
    ctrl->ok = ok;
  }
}

// ---------------- fused radix round: grid hist + ticket last-block scan ----------------
__global__ void __launch_bounds__(256)
radix_fused(Ctrl* __restrict__ ctrl, const float* __restrict__ buf,
            unsigned* __restrict__ gh, unsigned* __restrict__ tick,
            const float* __restrict__ ksc, int round, unsigned cap) {
  __shared__ unsigned h[256];
  __shared__ unsigned lastflag;
  int t = threadIdx.x;
  h[t] = 0;
  if (t == 0) lastflag = 0;
  __syncthreads();
  unsigned m = min(ctrl->ok ? ctrl->wcount : ctrl->gcount, cap);
  unsigned pref = ctrl->spref;
  int shift = 24 - 8 * round;
  for (unsigned i = blockIdx.x * 256u + t; i < m; i += gridDim.x * 256u) {
    unsigned u = __float_as_uint(buf[i]);
    u ^= (u >> 31) ? 0xFFFFFFFFu : 0x80000000u;
    if (round == 0 || ((u ^ pref) >> (shift + 8)) == 0u)
      atomicAdd(&h[(u >> shift) & 255u], 1u);
  }
  __syncthreads();
  if (h[t]) atomicAdd(&gh[round * 256 + t], h[t]);
  __threadfence();
  if (t == 0)
    lastflag = (atomicAdd(&tick[round], 1u) == gridDim.x - 1u) ? 1u : 0u;
  __syncthreads();
  if (!lastflag) return;
  // last block scans this round's 256 bins (device-scope reads)
  unsigned rank = (round == 0) ? (ctrl->ok ? ctrl->wrank : ctrl->rank) : ctrl->srank;
  unsigned c = atomicAdd(&gh[round * 256 + t], 0u);
  h[t] = c;
  __syncthreads();
  for (int off = 1; off < 256; off <<= 1) {
    unsigned v = h[t];
    unsigned add = (t >= off) ? h[t - off] : 0u;
    __syncthreads();
    h[t] = v + add;
    __syncthreads();
  }
  unsigned incl = h[t], excl = incl - c;
  if (rank >= excl && rank < incl) {
    unsigned np = pref | ((unsigned)t << shift);
    ctrl->spref = np;
    ctrl->srank = rank - excl;
    if (round == 3) {
      unsigned u = (np & 0x80000000u) ? (np ^ 0x80000000u) : ~np;
      float med = __uint_as_float(u) + 100.0f;  // undo d-100 store (exact)
      ctrl->median = med;
      float base = -1.0f / med;
#pragma unroll
      for (int k = 0; k < KK; ++k) ctrl->scales[k] = base * ksc[k];
      ctrl->c2 = base * 0.5f * 1.44269504088896f;
      ctrl->use_pow = (ksc[0] == 0.5f && ksc[1] == 1.0f && ksc[2] == 2.0f &&
                       ksc[3] == 4.0f && ksc[4] == 8.0f) ? 1u : 0u;
    }
  }
}

// ---------------- finalize ----------------
__global__ void finalize_kernel(const double* __restrict__ S, float* __restrict__ out) {
  if (threadIdx.x == 0 && blockIdx.x == 0) {
    double offd = 1.0 / ((double)NN * (double)(NN - 1));
    double invK = 1.0 / (double)KK;
    double kxx = (S[0] * invK) - (double)NN;  // subtract diagonal (exp(0)=1, KK terms)
    double kyy = (S[1] * invK) - (double)NN;
    double kzz = S[2] * invK;
    double val = offd * (kxx + kyy) - 2.0 * kzz / ((double)NN * (double)NN);
    out[0] = (float)val;
  }
}

extern "C" void kernel_launch(void* const* d_in, const int* in_sizes, int n_in,
                              void* d_out, int out_size, void* d_ws, size_t ws_size,
                              hipStream_t stream) {
  const float* x = (const float*)d_in[0];
  const float* y = (const float*)d_in[1];
  const float* ksc = (const float*)d_in[2];

  char* ws = (char*)d_ws;
  double* S = (double*)ws;                 // 3 doubles @ 0
  unsigned* hist = (unsigned*)(ws + 64);   // 1024 u32  @ 64
  unsigned* gh = (unsigned*)(ws + 4160);   // 4*256 u32 @ 4160
  unsigned* tick = (unsigned*)(ws + 8256); // 8 u32     @ 8256
  Ctrl* ctrl = (Ctrl*)(ws + 8288);         // ~64B      @ 8288
  float* xn = (float*)(ws + 8448);
  float* yn = xn + NN;                     // ends @ 41216
  const size_t SPL = (size_t)NN * DD * 2;  // 512KB per split array
  short* xhi = (short*)(ws + 65536);
  short* xlo = (short*)(ws + 65536 + SPL);
  short* yhi = (short*)(ws + 65536 + 2 * SPL);
  short* ylo = (short*)(ws + 65536 + 3 * SPL);
  size_t bufoff = 65536 + 4 * SPL;         // @ 2162688
  float* buf = (float*)(ws + bufoff);

  size_t avail = (ws_size > bufoff) ? (ws_size - bufoff) / 4 : 0;
  unsigned cap = (unsigned)((avail < (size_t)(8u << 20)) ? avail : (size_t)(8u << 20));
  // narrow window around estimated median d~127.7; MODE1 exact fallback covers a miss
  int lobin, hibin;
  if (cap >= 450000u) { lobin = 254; hibin = 257; }  // d in [127.0, 128.5)
  else                { lobin = 254; hibin = 256; }  // d in [127.0, 128.0)

  hipMemsetAsync(ws, 0, 8448, stream);  // S, hist, gh, tick, ctrl

  splitnorms_kernel<<<512, 256, 0, stream>>>(x, y, xhi, xlo, yhi, ylo, xn, yn);
  pair_kernel<0><<<dim3(32, 32), 256, 0, stream>>>(xhi, xlo, yhi, ylo, xn, yn, hist, ctrl,
                                                   buf, S, lobin, hibin, cap);
  select_bin_kernel<<<1, 256, 0, stream>>>(hist, ctrl, lobin, hibin, cap);
  pair_kernel<1><<<dim3(32, 32), 256, 0, stream>>>(xhi, xlo, yhi, ylo, xn, yn, hist, ctrl,
                                                   buf, S, lobin, hibin, cap);
  for (int r = 0; r < 4; ++r)
    radix_fused<<<192, 256, 0, stream>>>(ctrl, buf, gh, tick, ksc, r, cap);
  pair_kernel<2><<<dim3(32, 32, 3), 256, 0, stream>>>(xhi, xlo, yhi, ylo, xn, yn, hist, ctrl,
                                                      buf, S, lobin, hibin, cap);
  finalize_kernel<<<1, 64, 0, stream>>>(S, (float*)d_out);
}

// Round 12
// 213.092 us; speedup vs baseline: 1.5560x; 1.0797x over previous
//
#include <hip/hip_runtime.h>

#define NN 4096
#define DD 64
#define KK 5
#define NBINS 1024
#define BINMUL 2.0f    // coarse bin width 0.5 over [0, 512)
#define RMED 8388607u  // (NN*NN - 1) / 2
#define MBUF_CAP 8192u // per-block LDS gather capacity (reuses tiles)

typedef short short8 __attribute__((ext_vector_type(8)));
typedef float f32x4 __attribute__((ext_vector_type(4)));

struct Ctrl {
  unsigned wcount;   // window-gathered candidate count (MODE 0)
  unsigned wover;    // 1 if any block overflowed its LDS gather buffer
  unsigned gcount;   // fallback-gathered candidate count (MODE 1)
  unsigned sel_bin;  // selected coarse bin
  unsigned rank;     // rank (0-based) within selected bin (fallback path)
  unsigned ok;       // 1 = window path valid (skip MODE 1)
  unsigned wrank;    // rank within window candidates (window path)
  unsigned spref;    // radix-select prefix (built over 4 rounds)
  unsigned srank;    // remaining rank within prefix
  unsigned use_pow;  // 1 if kernel_scales == [0.5,1,2,4,8]
  float median;
  float c2;          // base*0.5*log2(e)
  float scales[KK];  // base*kernel_scales[k] (general fallback)
};

__device__ inline float fast_exp2(float x) {
  float r;
  asm("v_exp_f32 %0, %1" : "=v"(r) : "v"(x));
  return r;
}
__device__ inline unsigned short bf16_rn(float f) {
  unsigned u = __float_as_uint(f);
  return (unsigned short)((u + 0x7FFFu + ((u >> 16) & 1u)) >> 16);
}
__device__ inline float bf16_val(unsigned short h) {
  return __uint_as_float(((unsigned)h) << 16);
}

// ---------------- fused split (f32 -> bf16 hi/lo) + row norms ----------------
__global__ void __launch_bounds__(256)
splitnorms_kernel(const float* __restrict__ x, const float* __restrict__ y,
                  short* __restrict__ xhi, short* __restrict__ xlo,
                  short* __restrict__ yhi, short* __restrict__ ylo,
                  float* __restrict__ xn, float* __restrict__ yn) {
  unsigned g = blockIdx.x * 256u + threadIdx.x;  // float4 id 0..131071
  const float* src; short *dhi, *dlo; float* nrm; unsigned local;
  if (g < 65536u) { src = x; dhi = xhi; dlo = xlo; nrm = xn; local = g; }
  else { src = y; dhi = yhi; dlo = ylo; nrm = yn; local = g - 65536u; }
  float4 v = *(const float4*)(src + (size_t)local * 4);
  unsigned short h0 = bf16_rn(v.x), h1 = bf16_rn(v.y), h2 = bf16_rn(v.z), h3 = bf16_rn(v.w);
  unsigned short l0 = bf16_rn(v.x - bf16_val(h0));
  unsigned short l1 = bf16_rn(v.y - bf16_val(h1));
  unsigned short l2 = bf16_rn(v.z - bf16_val(h2));
  unsigned short l3 = bf16_rn(v.w - bf16_val(h3));
  unsigned long long H = (unsigned long long)h0 | ((unsigned long long)h1 << 16) |
                         ((unsigned long long)h2 << 32) | ((unsigned long long)h3 << 48);
  unsigned long long L = (unsigned long long)l0 | ((unsigned long long)l1 << 16) |
                         ((unsigned long long)l2 << 32) | ((unsigned long long)l3 << 48);
  *(unsigned long long*)((char*)dhi + (size_t)local * 8) = H;
  *(unsigned long long*)((char*)dlo + (size_t)local * 8) = L;
  float part = v.x * v.x;
  part = fmaf(v.y, v.y, part);
  part = fmaf(v.z, v.z, part);
  part = fmaf(v.w, v.w, part);
#pragma unroll
  for (int off = 1; off < 16; off <<= 1) part += __shfl_xor(part, off);
  if ((threadIdx.x & 15) == 0) nrm[local >> 4] = part;
}

// ---------------- MFMA pair-tile kernel (round-8 code, verbatim) ----------------
// 128x128 tile per block, 4 waves of 64x64, bf16x2 split (hihi+hilo+lohi).
// LDS per matrix: [row][kind hi/lo][k] bf16, row stride 256B, XOR-swizzle ((row&7)<<4).
// MODE 0: coarse hist + window gather (stores d-100)
// MODE 1: fallback gather of sel_bin (stores d-100); early-exit if ctrl->ok
// MODE 2: kernel sums (z=0: xx, z=1: yy, z=2: zz)
template <int MODE>
__global__ void __launch_bounds__(256)
pair_kernel(const short* __restrict__ xhi, const short* __restrict__ xlo,
            const short* __restrict__ yhi, const short* __restrict__ ylo,
            const float* __restrict__ xn, const float* __restrict__ yn,
            unsigned* __restrict__ hist, Ctrl* __restrict__ ctrl,
            float* __restrict__ buf, double* __restrict__ S,
            int lobin, int hibin, unsigned cap) {
  if (MODE == 1) {
    if (ctrl->ok) return;  // window path succeeded
  }
  __shared__ __align__(16) char smem[65536];
  char* As = smem;
  char* Bs = smem + 32768;

  int t = threadIdx.x;
  int sel = (MODE == 2) ? blockIdx.z : 0;
  const short* Ah = (sel == 1) ? yhi : xhi;
  const short* Al = (sel == 1) ? ylo : xlo;
  const short* Bh = (sel == 0) ? xhi : yhi;
  const short* Bl = (sel == 0) ? xlo : ylo;
  const float* An = (sel == 1) ? yn : xn;
  const float* Bn = (sel == 0) ? xn : yn;

  int rowBase = blockIdx.y * 128;
  int colBase = blockIdx.x * 128;

  int lane = t & 63, wid = t >> 6;
  int wr = (wid >> 1) * 64, wc = (wid & 1) * 64;
  int lrow = lane & 15;
  int lk8 = (lane >> 4) * 8;
  int lswz = (lane & 7) << 4;

  // ---- stage 4x16KB tiles (coalesced 16B chunks, swizzled LDS writes) ----
  {
    const char* gAh = (const char*)Ah + (size_t)rowBase * 128;
    const char* gAl = (const char*)Al + (size_t)rowBase * 128;
    const char* gBh = (const char*)Bh + (size_t)colBase * 128;
    const char* gBl = (const char*)Bl + (size_t)colBase * 128;
    short8 rAh[4], rAl[4], rBh[4], rBl[4];
#pragma unroll
    for (int i = 0; i < 4; ++i) {
      int o = t * 16 + i * 4096;
      rAh[i] = *(const short8*)(gAh + o);
      rAl[i] = *(const short8*)(gAl + o);
      rBh[i] = *(const short8*)(gBh + o);
      rBl[i] = *(const short8*)(gBl + o);
    }
#pragma unroll
    for (int i = 0; i < 4; ++i) {
      int o = t * 16 + i * 4096;
      int rr = o >> 7;
      int cc = (o >> 4) & 7;
      int db = (rr * 256 + cc * 16) ^ ((rr & 7) << 4);
      *(short8*)(As + db) = rAh[i];
      *(short8*)(As + db + 128) = rAl[i];
      *(short8*)(Bs + db) = rBh[i];
      *(short8*)(Bs + db + 128) = rBl[i];
    }
  }
  __syncthreads();

  // ---- MFMA compute: acc += Ahi*Bhi + Ahi*Blo + Alo*Bhi ----
  f32x4 acc[4][4] = {};
#pragma unroll
  for (int kc = 0; kc < 2; ++kc) {
    short8 ah[4], al[4], bh[4], bl[4];
#pragma unroll
    for (int m = 0; m < 4; ++m) {
      int by = ((wr + m * 16 + lrow) * 256 + (lk8 + kc * 32) * 2) ^ lswz;
      ah[m] = *(const short8*)(As + by);
      al[m] = *(const short8*)(As + by + 128);
    }
#pragma unroll
    for (int n = 0; n < 4; ++n) {
      int by = ((wc + n * 16 + lrow) * 256 + (lk8 + kc * 32) * 2) ^ lswz;
      bh[n] = *(const short8*)(Bs + by);
      bl[n] = *(const short8*)(Bs + by + 128);
    }
#pragma unroll
    for (int m = 0; m < 4; ++m)
#pragma unroll
      for (int n = 0; n < 4; ++n) {
        acc[m][n] = __builtin_amdgcn_mfma_f32_16x16x32_bf16(ah[m], bh[n], acc[m][n], 0, 0, 0);
        acc[m][n] = __builtin_amdgcn_mfma_f32_16x16x32_bf16(ah[m], bl[n], acc[m][n], 0, 0, 0);
        acc[m][n] = __builtin_amdgcn_mfma_f32_16x16x32_bf16(al[m], bh[n], acc[m][n], 0, 0, 0);
      }
  }

  // C/D map (HW-verified m89): col = lane&15, row = (lane>>4)*4 + reg
  float anv[16], bnv[4];
#pragma unroll
  for (int m = 0; m < 4; ++m)
#pragma unroll
    for (int r = 0; r < 4; ++r)
      anv[m * 4 + r] = An[rowBase + wr + m * 16 + (lane >> 4) * 4 + r];
#pragma unroll
  for (int n = 0; n < 4; ++n) bnv[n] = Bn[colBase + wc + n * 16 + lrow];

  __syncthreads();  // all LDS fragment reads complete; smem reusable

  if (MODE == 0 || MODE == 1) {
    unsigned* h = (unsigned*)Bs;   // 4KB hist (MODE 0)
    float* mbuf = (float*)As;      // 8192-float gather buffer
    __shared__ unsigned bcnt, gbase;
    if (MODE == 0)
      for (int i = t; i < NBINS; i += 256) h[i] = 0;
    if (t == 0) bcnt = 0;
    __syncthreads();
    unsigned sb = (MODE == 1) ? ctrl->sel_bin : 0u;
#pragma unroll
    for (int m = 0; m < 4; ++m)
#pragma unroll
      for (int n = 0; n < 4; ++n)
#pragma unroll
        for (int r = 0; r < 4; ++r) {
          float d = (anv[m * 4 + r] + bnv[n]) - 2.0f * acc[m][n][r];
          int b = (int)(d * BINMUL);
          b = min(max(b, 0), NBINS - 1);
          if (MODE == 0) {
            atomicAdd(&h[b], 1u);
            if (b >= lobin && b < hibin) {
              unsigned idx = atomicAdd(&bcnt, 1u);
              if (idx < MBUF_CAP) mbuf[idx] = d - 100.0f;  // exact (d in [100,200])
              else ctrl->wover = 1u;
            }
          } else {
            if ((unsigned)b == sb) {
              unsigned idx = atomicAdd(&bcnt, 1u);
              if (idx < MBUF_CAP) mbuf[idx] = d - 100.0f;
            }
          }
        }
    __syncthreads();
    if (MODE == 0)
      for (int i = t; i < NBINS; i += 256)
        if (h[i]) atomicAdd(&hist[i], h[i]);
    unsigned cnt = min(bcnt, MBUF_CAP);
    if (t == 0) gbase = atomicAdd(MODE == 0 ? &ctrl->wcount : &ctrl->gcount, cnt);
    __syncthreads();
    for (unsigned i = t; i < cnt; i += 256) {
      unsigned gi = gbase + i;
      if (gi < cap) buf[gi] = mbuf[i];
    }
  }

  if (MODE == 2) {
    float s = 0.f;
    if (ctrl->use_pow) {
      float c2 = ctrl->c2;
#pragma unroll
      for (int m = 0; m < 4; ++m)
#pragma unroll
        for (int n = 0; n < 4; ++n)
#pragma unroll
          for (int r = 0; r < 4; ++r) {
            float d = (anv[m * 4 + r] + bnv[n]) - 2.0f * acc[m][n][r];
            float u = fast_exp2(d * c2);  // exp(d*base*0.5)
            float u2 = u * u, u4 = u2 * u2, u8 = u4 * u4, u16 = u8 * u8;
            s += ((u + u2) + (u4 + u8)) + u16;
          }
    } else {
      float sc[KK];
#pragma unroll
      for (int k = 0; k < KK; ++k) sc[k] = ctrl->scales[k];
#pragma unroll
      for (int m = 0; m < 4; ++m)
#pragma unroll
        for (int n = 0; n < 4; ++n)
#pragma unroll
          for (int r = 0; r < 4; ++r) {
            float d = (anv[m * 4 + r] + bnv[n]) - 2.0f * acc[m][n][r];
            float e = 0.f;
#pragma unroll
            for (int k = 0; k < KK; ++k) e += expf(d * sc[k]);
            s += e;
          }
    }
    // diagonal handled analytically in finalize
    double sd = (double)s;
#pragma unroll
    for (int off = 32; off > 0; off >>= 1) sd += __shfl_down(sd, off);
    double* wsum = (double*)As;
    if ((t & 63) == 0) wsum[wid] = sd;
    __syncthreads();
    if (t == 0) atomicAdd(&S[sel], (wsum[0] + wsum[1]) + (wsum[2] + wsum[3]));
  }
}

// ---------------- find coarse bin of rank RMED (round-8 code, verbatim) ----------------
__global__ void __launch_bounds__(256)
select_bin_kernel(const unsigned* __restrict__ hist, Ctrl* __restrict__ ctrl,
                  int lobin, int hibin, unsigned cap) {
  __shared__ unsigned ps[256];
  __shared__ unsigned s_cumlo;
  int t = threadIdx.x;
  unsigned loc[NBINS / 256];
  unsigned s = 0;
#pragma unroll
  for (int i = 0; i < NBINS / 256; ++i) {
    loc[i] = hist[t * (NBINS / 256) + i];
    s += loc[i];
  }
  ps[t] = s;
  __syncthreads();
  for (int off = 1; off < 256; off <<= 1) {
    unsigned v = ps[t];
    unsigned add = (t >= off) ? ps[t - off] : 0u;
    __syncthreads();
    ps[t] = v + add;
    __syncthreads();
  }
  unsigned incl = ps[t], excl = incl - s;
  if (t == (lobin >> 2)) {  // exclusive cum below bin `lobin`
    unsigned c = excl;
    for (int i = 0; i < (lobin & 3); ++i) c += loc[i];
    s_cumlo = c;
  }
  __syncthreads();
  if (RMED >= excl && RMED < incl) {
    unsigned rank = RMED - excl;
    int bsel = -1;
#pragma unroll
    for (int i = 0; i < NBINS / 256; ++i) {
      if (bsel < 0) {
        if (rank < loc[i]) bsel = t * (NBINS / 256) + i;
        else rank -= loc[i];
      }
    }
    ctrl->sel_bin = (unsigned)bsel;
    ctrl->rank = rank;
    unsigned wrank = RMED - s_cumlo;
    unsigned ok = (bsel >= lobin && bsel < hibin && ctrl->wover == 0u &&
                   ctrl->wcount <= cap && wrank < ctrl->wcount) ? 1u : 0u;
    ctrl->wrank = wrank;
    ctrl->ok = ok;
  }
}

// ---------------- fused radix round: grid hist + ticket last-block scan ----------------
__global__ void __launch_bounds__(256)
radix_fused(Ctrl* __restrict__ ctrl, const float* __restrict__ buf,
            unsigned* __restrict__ gh, unsigned* __restrict__ tick,
            const float* __restrict__ ksc, int round, unsigned cap) {
  __shared__ unsigned h[256];
  __shared__ unsigned lastflag;
  int t = threadIdx.x;
  h[t] = 0;
  if (t == 0) lastflag = 0;
  __syncthreads();
  unsigned m = min(ctrl->ok ? ctrl->wcount : ctrl->gcount, cap);
  unsigned pref = ctrl->spref;
  int shift = 24 - 8 * round;
  for (unsigned i = blockIdx.x * 256u + t; i < m; i += gridDim.x * 256u) {
    unsigned u = __float_as_uint(buf[i]);
    u ^= (u >> 31) ? 0xFFFFFFFFu : 0x80000000u;
    if (round == 0 || ((u ^ pref) >> (shift + 8)) == 0u)
      atomicAdd(&h[(u >> shift) & 255u], 1u);
  }
  __syncthreads();
  if (h[t]) atomicAdd(&gh[round * 256 + t], h[t]);
  __threadfence();
  if (t == 0)
    lastflag = (atomicAdd(&tick[round], 1u) == gridDim.x - 1u) ? 1u : 0u;
  __syncthreads();
  if (!lastflag) return;
  // last block scans this round's 256 bins (device-scope reads)
  unsigned rank = (round == 0) ? (ctrl->ok ? ctrl->wrank : ctrl->rank) : ctrl->srank;
  unsigned c = atomicAdd(&gh[round * 256 + t], 0u);
  h[t] = c;
  __syncthreads();
  for (int off = 1; off < 256; off <<= 1) {
    unsigned v = h[t];
    unsigned add = (t >= off) ? h[t - off] : 0u;
    __syncthreads();
    h[t] = v + add;
    __syncthreads();
  }
  unsigned incl = h[t], excl = incl - c;
  if (rank >= excl && rank < incl) {
    unsigned np = pref | ((unsigned)t << shift);
    ctrl->spref = np;
    ctrl->srank = rank - excl;
    if (round == 3) {
      unsigned u = (np & 0x80000000u) ? (np ^ 0x80000000u) : ~np;
      float med = __uint_as_float(u) + 100.0f;  // undo d-100 store (exact)
      ctrl->median = med;
      float base = -1.0f / med;
#pragma unroll
      for (int k = 0; k < KK; ++k) ctrl->scales[k] = base * ksc[k];
      ctrl->c2 = base * 0.5f * 1.44269504088896f;
      ctrl->use_pow = (ksc[0] == 0.5f && ksc[1] == 1.0f && ksc[2] == 2.0f &&
                       ksc[3] == 4.0f && ksc[4] == 8.0f) ? 1u : 0u;
    }
  }
}

// ---------------- finalize ----------------
__global__ void finalize_kernel(const double* __restrict__ S, float* __restrict__ out) {
  if (threadIdx.x == 0 && blockIdx.x == 0) {
    double offd = 1.0 / ((double)NN * (double)(NN - 1));
    double invK = 1.0 / (double)KK;
    double kxx = (S[0] * invK) - (double)NN;  // subtract diagonal (exp(0)=1, KK terms)
    double kyy = (S[1] * invK) - (double)NN;
    double kzz = S[2] * invK;
    double val = offd * (kxx + kyy) - 2.0 * kzz / ((double)NN * (double)NN);
    out[0] = (float)val;
  }
}

extern "C" void kernel_launch(void* const* d_in, const int* in_sizes, int n_in,
                              void* d_out, int out_size, void* d_ws, size_t ws_size,
                              hipStream_t stream) {
  const float* x = (const float*)d_in[0];
  const float* y = (const float*)d_in[1];
  const float* ksc = (const float*)d_in[2];

  char* ws = (char*)d_ws;
  double* S = (double*)ws;                 // 3 doubles @ 0
  unsigned* hist = (unsigned*)(ws + 64);   // 1024 u32  @ 64
  unsigned* gh = (unsigned*)(ws + 4160);   // 4*256 u32 @ 4160
  unsigned* tick = (unsigned*)(ws + 8256); // 8 u32     @ 8256
  Ctrl* ctrl = (Ctrl*)(ws + 8288);         // ~64B      @ 8288
  float* xn = (float*)(ws + 8448);
  float* yn = xn + NN;                     // ends @ 41216
  const size_t SPL = (size_t)NN * DD * 2;  // 512KB per split array
  short* xhi = (short*)(ws + 65536);
  short* xlo = (short*)(ws + 65536 + SPL);
  short* yhi = (short*)(ws + 65536 + 2 * SPL);
  short* ylo = (short*)(ws + 65536 + 3 * SPL);
  size_t bufoff = 65536 + 4 * SPL;         // @ 2162688
  float* buf = (float*)(ws + bufoff);

  size_t avail = (ws_size > bufoff) ? (ws_size - bufoff) / 4 : 0;
  unsigned cap = (unsigned)((avail < (size_t)(8u << 20)) ? avail : (size_t)(8u << 20));
  // window centered on TRUE median: d = 2*median(chi2_64) ~ 126.67 (not 127.7!
  // r9-r11 windows missed it -> fallback full passes). MODE1 covers any miss.
  int lobin, hibin;
  if (cap >= 450000u) { lobin = 252; hibin = 255; }  // d in [126.0, 127.5)
  else                { lobin = 252; hibin = 254; }  // d in [126.0, 127.0)

  hipMemsetAsync(ws, 0, 8448, stream);  // S, hist, gh, tick, ctrl

  splitnorms_kernel<<<512, 256, 0, stream>>>(x, y, xhi, xlo, yhi, ylo, xn, yn);
  pair_kernel<0><<<dim3(32, 32), 256, 0, stream>>>(xhi, xlo, yhi, ylo, xn, yn, hist, ctrl,
                                                   buf, S, lobin, hibin, cap);
  select_bin_kernel<<<1, 256, 0, stream>>>(hist, ctrl, lobin, hibin, cap);
  pair_kernel<1><<<dim3(32, 32), 256, 0, stream>>>(xhi, xlo, yhi, ylo, xn, yn, hist, ctrl,
                                                   buf, S, lobin, hibin, cap);
  for (int r = 0; r < 4; ++r)
    radix_fused<<<192, 256, 0, stream>>>(ctrl, buf, gh, tick, ksc, r, cap);
  pair_kernel<2><<<dim3(32, 32, 3), 256, 0, stream>>>(xhi, xlo, yhi, ylo, xn, yn, hist, ctrl,
                                                      buf, S, lobin, hibin, cap);
  finalize_kernel<<<1, 64, 0, stream>>>(S, (float*)d_out);
}

// Round 13
// 200.740 us; speedup vs baseline: 1.6517x; 1.0615x over previous
//
#include <hip/hip_runtime.h>

#define NN 4096
#define DD 64
#define KK 5
#define NBINS 1024
#define BINMUL 2.0f    // coarse bin width 0.5 over [0, 512)
#define RMED 8388607u  // (NN*NN - 1) / 2
#define MBUF_CAP 7164u // gather capacity within the 32KB smem block

typedef short short8 __attribute__((ext_vector_type(8)));
typedef float f32x4 __attribute__((ext_vector_type(4)));

struct Ctrl {
  unsigned wcount;   // window-gathered candidate count (MODE 0)
  unsigned wover;    // 1 if any block overflowed its LDS gather buffer
  unsigned gcount;   // fallback-gathered candidate count (MODE 1)
  unsigned sel_bin;  // selected coarse bin
  unsigned rank;     // rank (0-based) within selected bin (fallback path)
  unsigned ok;       // 1 = window path valid (skip MODE 1)
  unsigned wrank;    // rank within window candidates (window path)
  unsigned spref;    // radix-select prefix
  unsigned srank;    // remaining rank within prefix
  unsigned use_pow;  // 1 if kernel_scales == [0.5,1,2,4,8]
  unsigned skip0;    // 1 = radix round 0 pre-resolved (single-binade window)
  float median;
  float c2;          // base*0.5*log2(e)
  float scales[KK];  // base*kernel_scales[k] (general fallback)
};

__device__ inline float fast_exp2(float x) {
  float r;
  asm("v_exp_f32 %0, %1" : "=v"(r) : "v"(x));
  return r;
}
__device__ inline unsigned short bf16_rn(float f) {
  unsigned u = __float_as_uint(f);
  return (unsigned short)((u + 0x7FFFu + ((u >> 16) & 1u)) >> 16);
}
__device__ inline float bf16_val(unsigned short h) {
  return __uint_as_float(((unsigned)h) << 16);
}

// ---- fused split (f32 -> bf16 hi/lo, k-half-permuted layout) + row norms ----
// Split arrays are stored as [khalf 0/1][row 0..NN-1][32 shorts] so pair_kernel
// phase p reads a fully CONTIGUOUS 8KB slab per matrix (fixes r9's stride-2).
__global__ void __launch_bounds__(256)
splitnorms_kernel(const float* __restrict__ x, const float* __restrict__ y,
                  short* __restrict__ xhi, short* __restrict__ xlo,
                  short* __restrict__ yhi, short* __restrict__ ylo,
                  float* __restrict__ xn, float* __restrict__ yn) {
  unsigned g = blockIdx.x * 256u + threadIdx.x;  // float4 id 0..131071
  const float* src; short *dhi, *dlo; float* nrm; unsigned local;
  if (g < 65536u) { src = x; dhi = xhi; dlo = xlo; nrm = xn; local = g; }
  else { src = y; dhi = yhi; dlo = ylo; nrm = yn; local = g - 65536u; }
  float4 v = *(const float4*)(src + (size_t)local * 4);
  unsigned short h0 = bf16_rn(v.x), h1 = bf16_rn(v.y), h2 = bf16_rn(v.z), h3 = bf16_rn(v.w);
  unsigned short l0 = bf16_rn(v.x - bf16_val(h0));
  unsigned short l1 = bf16_rn(v.y - bf16_val(h1));
  unsigned short l2 = bf16_rn(v.z - bf16_val(h2));
  unsigned short l3 = bf16_rn(v.w - bf16_val(h3));
  unsigned long long H = (unsigned long long)h0 | ((unsigned long long)h1 << 16) |
                         ((unsigned long long)h2 << 32) | ((unsigned long long)h3 << 48);
  unsigned long long L = (unsigned long long)l0 | ((unsigned long long)l1 << 16) |
                         ((unsigned long long)l2 << 32) | ((unsigned long long)l3 << 48);
  unsigned row = local >> 4, kc4 = local & 15;
  size_t dst = (((size_t)(kc4 >> 3) * NN + row) * 32 + (kc4 & 7) * 4) * 2;  // bytes
  *(unsigned long long*)((char*)dhi + dst) = H;
  *(unsigned long long*)((char*)dlo + dst) = L;
  float part = v.x * v.x;
  part = fmaf(v.y, v.y, part);
  part = fmaf(v.z, v.z, part);
  part = fmaf(v.w, v.w, part);
#pragma unroll
  for (int off = 1; off < 16; off <<= 1) part += __shfl_xor(part, off);
  if ((threadIdx.x & 15) == 0) nrm[local >> 4] = part;
}

// ---------------- MFMA pair-tile kernel (32KB LDS, 2 K-phases) ----------------
// 128x128 tile, 4 waves of 64x64, bf16x2 split (hihi+hilo+lohi).
// LDS per phase: 4 tiles x [128 rows][32 k] bf16 (64B rows), slot swizzle
// slot^=(row&3) on 16B slots -> conflict-free staging writes AND fragment reads.
// smem layout (one 32768B block, 5 blocks/CU): [0,28656) mbuf | [28656,28672) ctl
// | [28672,32768) hist.
// MODE 0: coarse hist + window gather (stores d-100)
// MODE 1: fallback gather of sel_bin; early-exit if ctrl->ok
// MODE 2: kernel sums (z=0: xx, z=1: yy, z=2: zz)
template <int MODE>
__global__ void __launch_bounds__(256)
pair_kernel(const short* __restrict__ xhi, const short* __restrict__ xlo,
            const short* __restrict__ yhi, const short* __restrict__ ylo,
            const float* __restrict__ xn, const float* __restrict__ yn,
            unsigned* __restrict__ hist, Ctrl* __restrict__ ctrl,
            float* __restrict__ buf, double* __restrict__ S,
            int lobin, int hibin, unsigned cap) {
  if (MODE == 1) {
    if (ctrl->ok) return;  // window path succeeded
  }
  __shared__ __align__(16) char smem[32768];

  int t = threadIdx.x;
  int sel = (MODE == 2) ? blockIdx.z : 0;
  const short* Ah = (sel == 1) ? yhi : xhi;
  const short* Al = (sel == 1) ? ylo : xlo;
  const short* Bh = (sel == 0) ? xhi : yhi;
  const short* Bl = (sel == 0) ? xlo : ylo;
  const float* An = (sel == 1) ? yn : xn;
  const float* Bn = (sel == 0) ? xn : yn;

  int rowBase = blockIdx.y * 128;
  int colBase = blockIdx.x * 128;

  int lane = t & 63, wid = t >> 6;
  int wr = (wid >> 1) * 64, wc = (wid & 1) * 64;
  int lrow = lane & 15;
  int koffs = (((lane >> 4) ^ (lane & 3)) << 4);  // swizzled 16B slot

  f32x4 acc[4][4] = {};
#pragma unroll
  for (int p = 0; p < 2; ++p) {
    const char* s0 = (const char*)Ah + ((size_t)p * NN + rowBase) * 64;
    const char* s1 = (const char*)Al + ((size_t)p * NN + rowBase) * 64;
    const char* s2 = (const char*)Bh + ((size_t)p * NN + colBase) * 64;
    const char* s3 = (const char*)Bl + ((size_t)p * NN + colBase) * 64;
    short8 rg[8];
    rg[0] = *(const short8*)(s0 + t * 16);
    rg[1] = *(const short8*)(s0 + t * 16 + 4096);
    rg[2] = *(const short8*)(s1 + t * 16);
    rg[3] = *(const short8*)(s1 + t * 16 + 4096);
    rg[4] = *(const short8*)(s2 + t * 16);
    rg[5] = *(const short8*)(s2 + t * 16 + 4096);
    rg[6] = *(const short8*)(s3 + t * 16);
    rg[7] = *(const short8*)(s3 + t * 16 + 4096);
    if (p) __syncthreads();  // phase-0 fragment reads all consumed
#pragma unroll
    for (int i = 0; i < 8; ++i) {
      int cr = t * 16 + (i & 1) * 4096;  // byte offset in slab
      int row = cr >> 6, slot = (cr >> 4) & 3;
      int db = (i >> 1) * 8192 + row * 64 + ((slot ^ (row & 3)) << 4);
      *(short8*)(smem + db) = rg[i];
    }
    __syncthreads();
    short8 bh[4], bl[4];
#pragma unroll
    for (int n = 0; n < 4; ++n) {
      int rb = (wc + n * 16 + lrow) * 64 + koffs;  // row&3 == lane&3
      bh[n] = *(const short8*)(smem + 16384 + rb);
      bl[n] = *(const short8*)(smem + 24576 + rb);
    }
#pragma unroll
    for (int m = 0; m < 4; ++m) {
      int rb = (wr + m * 16 + lrow) * 64 + koffs;
      short8 ah = *(const short8*)(smem + rb);
      short8 al = *(const short8*)(smem + 8192 + rb);
#pragma unroll
      for (int n = 0; n < 4; ++n) {
        acc[m][n] = __builtin_amdgcn_mfma_f32_16x16x32_bf16(ah, bh[n], acc[m][n], 0, 0, 0);
        acc[m][n] = __builtin_amdgcn_mfma_f32_16x16x32_bf16(ah, bl[n], acc[m][n], 0, 0, 0);
        acc[m][n] = __builtin_amdgcn_mfma_f32_16x16x32_bf16(al, bh[n], acc[m][n], 0, 0, 0);
      }
    }
  }

  // C/D map (HW-verified m89): col = lane&15, row = (lane>>4)*4 + reg
  float anv[16], bnv[4];
#pragma unroll
  for (int m = 0; m < 4; ++m)
#pragma unroll
    for (int r = 0; r < 4; ++r)
      anv[m * 4 + r] = An[rowBase + wr + m * 16 + (lane >> 4) * 4 + r];
#pragma unroll
  for (int n = 0; n < 4; ++n) bnv[n] = Bn[colBase + wc + n * 16 + lrow];

  __syncthreads();  // all LDS fragment reads complete; smem reusable

  unsigned* bcnt = (unsigned*)(smem + 28656);
  unsigned* gbase = (unsigned*)(smem + 28660);

  if (MODE == 0 || MODE == 1) {
    unsigned* h = (unsigned*)(smem + 28672);  // 1024 u32 (MODE 0)
    float* mbuf = (float*)smem;               // MBUF_CAP floats
    if (MODE == 0)
      for (int i = t; i < NBINS; i += 256) h[i] = 0;
    if (t == 0) *bcnt = 0;
    __syncthreads();
    unsigned sb = (MODE == 1) ? ctrl->sel_bin : 0u;
#pragma unroll
    for (int m = 0; m < 4; ++m)
#pragma unroll
      for (int n = 0; n < 4; ++n)
#pragma unroll
        for (int r = 0; r < 4; ++r) {
          float d = (anv[m * 4 + r] + bnv[n]) - 2.0f * acc[m][n][r];
          int b = (int)(d * BINMUL);
          b = min(max(b, 0), NBINS - 1);
          if (MODE == 0) {
            atomicAdd(&h[b], 1u);
            if (b >= lobin && b < hibin) {
              unsigned idx = atomicAdd(bcnt, 1u);
              if (idx < MBUF_CAP) mbuf[idx] = d - 100.0f;  // exact (d in [100,200])
              else ctrl->wover = 1u;
            }
          } else {
            if ((unsigned)b == sb) {
              unsigned idx = atomicAdd(bcnt, 1u);
              if (idx < MBUF_CAP) mbuf[idx] = d - 100.0f;
            }
          }
        }
    __syncthreads();
    if (MODE == 0)
      for (int i = t; i < NBINS; i += 256)
        if (h[i]) atomicAdd(&hist[i], h[i]);
    unsigned cnt = min(*bcnt, MBUF_CAP);
    if (t == 0) *gbase = atomicAdd(MODE == 0 ? &ctrl->wcount : &ctrl->gcount, cnt);
    __syncthreads();
    unsigned gb = *gbase;
    for (unsigned i = t; i < cnt; i += 256) {
      unsigned gi = gb + i;
      if (gi < cap) buf[gi] = mbuf[i];
    }
  }

  if (MODE == 2) {
    float s = 0.f;
    if (ctrl->use_pow) {
      float c2 = ctrl->c2, m2c2 = -2.0f * c2;
      float bnvc[4];
#pragma unroll
      for (int n = 0; n < 4; ++n) bnvc[n] = bnv[n] * c2;
#pragma unroll
      for (int i = 0; i < 16; ++i) anv[i] *= c2;
#pragma unroll
      for (int m = 0; m < 4; ++m)
#pragma unroll
        for (int n = 0; n < 4; ++n)
#pragma unroll
          for (int r = 0; r < 4; ++r) {
            float arg = fmaf(acc[m][n][r], m2c2, anv[m * 4 + r] + bnvc[n]);
            float u = fast_exp2(arg);     // exp(d*base*0.5)
            float u2 = u * u;
            float a = fmaf(u, u, u);      // u + u^2
            float u4 = u2 * u2, u8 = u4 * u4;
            float b = fmaf(u8, u8, u8);   // u^8 + u^16
            s += a; s += u4; s += b;
          }
    } else {
      float sc[KK];
#pragma unroll
      for (int k = 0; k < KK; ++k) sc[k] = ctrl->scales[k];
#pragma unroll
      for (int m = 0; m < 4; ++m)
#pragma unroll
        for (int n = 0; n < 4; ++n)
#pragma unroll
          for (int r = 0; r < 4; ++r) {
            float d = (anv[m * 4 + r] + bnv[n]) - 2.0f * acc[m][n][r];
            float e = 0.f;
#pragma unroll
            for (int k = 0; k < KK; ++k) e += expf(d * sc[k]);
            s += e;
          }
    }
    // diagonal handled analytically in finalize
    double sd = (double)s;
#pragma unroll
    for (int off = 32; off > 0; off >>= 1) sd += __shfl_down(sd, off);
    double* wsum = (double*)smem;
    if ((t & 63) == 0) wsum[wid] = sd;
    __syncthreads();
    if (t == 0) atomicAdd(&S[sel], (wsum[0] + wsum[1]) + (wsum[2] + wsum[3]));
  }
}

// ---------------- find coarse bin of rank RMED ----------------
__global__ void __launch_bounds__(256)
select_bin_kernel(const unsigned* __restrict__ hist, Ctrl* __restrict__ ctrl,
                  int lobin, int hibin, unsigned cap) {
  __shared__ unsigned ps[256];
  __shared__ unsigned s_cumlo;
  int t = threadIdx.x;
  unsigned loc[NBINS / 256];
  unsigned s = 0;
#pragma unroll
  for (int i = 0; i < NBINS / 256; ++i) {
    loc[i] = hist[t * (NBINS / 256) + i];
    s += loc[i];
  }
  ps[t] = s;
  __syncthreads();
  for (int off = 1; off < 256; off <<= 1) {
    unsigned v = ps[t];
    unsigned add = (t >= off) ? ps[t - off] : 0u;
    __syncthreads();
    ps[t] = v + add;
    __syncthreads();
  }
  unsigned incl = ps[t], excl = incl - s;
  if (t == (lobin >> 2)) {  // exclusive cum below bin `lobin`
    unsigned c = excl;
    for (int i = 0; i < (lobin & 3); ++i) c += loc[i];
    s_cumlo = c;
  }
  __syncthreads();
  if (RMED >= excl && RMED < incl) {
    unsigned rank = RMED - excl;
    int bsel = -1;
#pragma unroll
    for (int i = 0; i < NBINS / 256; ++i) {
      if (bsel < 0) {
        if (rank < loc[i]) bsel = t * (NBINS / 256) + i;
        else rank -= loc[i];
      }
    }
    ctrl->sel_bin = (unsigned)bsel;
    ctrl->rank = rank;
    unsigned wrank = RMED - s_cumlo;
    unsigned ok = (bsel >= lobin && bsel < hibin && ctrl->wover == 0u &&
                   ctrl->wcount <= cap && wrank < ctrl->wcount) ? 1u : 0u;
    ctrl->wrank = wrank;
    ctrl->ok = ok;
    // single-binade window: d-100 in [16,32) => ordered top byte 0xC1; round 0 known
    if (ok && lobin >= 232 && hibin <= 264) {
      ctrl->spref = 0xC1000000u;
      ctrl->srank = wrank;
      ctrl->skip0 = 1u;
    }
  }
}

// ---------------- fused radix round: grid hist + ticket last-block scan ----------------
__global__ void __launch_bounds__(256)
radix_fused(Ctrl* __restrict__ ctrl, const float* __restrict__ buf,
            unsigned* __restrict__ gh, unsigned* __restrict__ tick,
            const float* __restrict__ ksc, int round, unsigned cap) {
  if (round == 0 && ctrl->skip0) return;  // round 0 pre-resolved by select_bin
  __shared__ unsigned h[256];
  __shared__ unsigned lastflag;
  int t = threadIdx.x;
  h[t] = 0;
  if (t == 0) lastflag = 0;
  __syncthreads();
  unsigned m = min(ctrl->ok ? ctrl->wcount : ctrl->gcount, cap);
  unsigned pref = ctrl->spref;
  int shift = 24 - 8 * round;
  for (unsigned i = blockIdx.x * 256u + t; i < m; i += gridDim.x * 256u) {
    unsigned u = __float_as_uint(buf[i]);
    u ^= (u >> 31) ? 0xFFFFFFFFu : 0x80000000u;
    if (round == 0 || ((u ^ pref) >> (shift + 8)) == 0u)
      atomicAdd(&h[(u >> shift) & 255u], 1u);
  }
  __syncthreads();
  if (h[t]) atomicAdd(&gh[round * 256 + t], h[t]);
  __threadfence();
  if (t == 0)
    lastflag = (atomicAdd(&tick[round], 1u) == gridDim.x - 1u) ? 1u : 0u;
  __syncthreads();
  if (!lastflag) return;
  // last block scans this round's 256 bins (device-scope reads)
  unsigned rank = (round == 0) ? (ctrl->ok ? ctrl->wrank : ctrl->rank) : ctrl->srank;
  unsigned c = atomicAdd(&gh[round * 256 + t], 0u);
  h[t] = c;
  __syncthreads();
  for (int off = 1; off < 256; off <<= 1) {
    unsigned v = h[t];
    unsigned add = (t >= off) ? h[t - off] : 0u;
    __syncthreads();
    h[t] = v + add;
    __syncthreads();
  }
  unsigned incl = h[t], excl = incl - c;
  if (rank >= excl && rank < incl) {
    unsigned np = pref | ((unsigned)t << shift);
    ctrl->spref = np;
    ctrl->srank = rank - excl;
    if (round == 3) {
      unsigned u = (np & 0x80000000u) ? (np ^ 0x80000000u) : ~np;
      float med = __uint_as_float(u) + 100.0f;  // undo d-100 store (exact)
      ctrl->median = med;
      float base = -1.0f / med;
#pragma unroll
      for (int k = 0; k < KK; ++k) ctrl->scales[k] = base * ksc[k];
      ctrl->c2 = base * 0.5f * 1.44269504088896f;
      ctrl->use_pow = (ksc[0] == 0.5f && ksc[1] == 1.0f && ksc[2] == 2.0f &&
                       ksc[3] == 4.0f && ksc[4] == 8.0f) ? 1u : 0u;
    }
  }
}

// ---------------- finalize ----------------
__global__ void finalize_kernel(const double* __restrict__ S, float* __restrict__ out) {
  if (threadIdx.x == 0 && blockIdx.x == 0) {
    double offd = 1.0 / ((double)NN * (double)(NN - 1));
    double invK = 1.0 / (double)KK;
    double kxx = (S[0] * invK) - (double)NN;  // subtract diagonal (exp(0)=1, KK terms)
    double kyy = (S[1] * invK) - (double)NN;
    double kzz = S[2] * invK;
    double val = offd * (kxx + kyy) - 2.0 * kzz / ((double)NN * (double)NN);
    out[0] = (float)val;
  }
}

extern "C" void kernel_launch(void* const* d_in, const int* in_sizes, int n_in,
                              void* d_out, int out_size, void* d_ws, size_t ws_size,
                              hipStream_t stream) {
  const float* x = (const float*)d_in[0];
  const float* y = (const float*)d_in[1];
  const float* ksc = (const float*)d_in[2];

  char* ws = (char*)d_ws;
  double* S = (double*)ws;                 // 3 doubles @ 0
  unsigned* hist = (unsigned*)(ws + 64);   // 1024 u32  @ 64
  unsigned* gh = (unsigned*)(ws + 4160);   // 4*256 u32 @ 4160
  unsigned* tick = (unsigned*)(ws + 8256); // 8 u32     @ 8256
  Ctrl* ctrl = (Ctrl*)(ws + 8288);         // ~72B      @ 8288
  float* xn = (float*)(ws + 8448);
  float* yn = xn + NN;                     // ends @ 41216
  const size_t SPL = (size_t)NN * DD * 2;  // 512KB per split array
  short* xhi = (short*)(ws + 65536);
  short* xlo = (short*)(ws + 65536 + SPL);
  short* yhi = (short*)(ws + 65536 + 2 * SPL);
  short* ylo = (short*)(ws + 65536 + 3 * SPL);
  size_t bufoff = 65536 + 4 * SPL;         // @ 2162688
  float* buf = (float*)(ws + bufoff);

  size_t avail = (ws_size > bufoff) ? (ws_size - bufoff) / 4 : 0;
  unsigned cap = (unsigned)((avail < (size_t)(8u << 20)) ? avail : (size_t)(8u << 20));
  // window centered on true median d = 2*median(chi2_64) ~ 126.67 (validated r12)
  int lobin, hibin;
  if (cap >= 450000u) { lobin = 252; hibin = 255; }  // d in [126.0, 127.5)
  else                { lobin = 252; hibin = 254; }  // d in [126.0, 127.0)

  hipMemsetAsync(ws, 0, 8448, stream);  // S, hist, gh, tick, ctrl

  splitnorms_kernel<<<512, 256, 0, stream>>>(x, y, xhi, xlo, yhi, ylo, xn, yn);
  pair_kernel<0><<<dim3(32, 32), 256, 0, stream>>>(xhi, xlo, yhi, ylo, xn, yn, hist, ctrl,
                                                   buf, S, lobin, hibin, cap);
  select_bin_kernel<<<1, 256, 0, stream>>>(hist, ctrl, lobin, hibin, cap);
  pair_kernel<1><<<dim3(32, 32), 256, 0, stream>>>(xhi, xlo, yhi, ylo, xn, yn, hist, ctrl,
                                                   buf, S, lobin, hibin, cap);
  for (int r = 0; r < 4; ++r)
    radix_fused<<<192, 256, 0, stream>>>(ctrl, buf, gh, tick, ksc, r, cap);
  pair_kernel<2><<<dim3(32, 32, 3), 256, 0, stream>>>(xhi, xlo, yhi, ylo, xn, yn, hist, ctrl,
                                                      buf, S, lobin, hibin, cap);
  finalize_kernel<<<1, 64, 0, stream>>>(S, (float*)d_out);
}